// Round 1
// baseline (2218.298 us; speedup 1.0000x reference)
//
#include <hip/hip_runtime.h>
#include <hip/hip_bf16.h>
#include <stdint.h>

#define LNUM 6
#define BB 8
#define TT 1024
#define CC 768
#define HH 12
#define HDIM 64
#define DFF 3072
#define VV 512
#define MM (BB*TT)

typedef __bf16 bf16x8 __attribute__((ext_vector_type(8)));
typedef float f32x4 __attribute__((ext_vector_type(4)));

__device__ __forceinline__ uint16_t f2b(float f) {
  uint32_t u = __float_as_uint(f);
  u += 0x7FFFu + ((u >> 16) & 1u);
  return (uint16_t)(u >> 16);
}

__device__ __forceinline__ void gld16(const uint16_t* g, uint16_t* l) {
  __builtin_amdgcn_global_load_lds(
      (const __attribute__((address_space(1))) uint32_t*)g,
      (__attribute__((address_space(3))) uint32_t*)l, 16, 0, 0);
}

__device__ __forceinline__ f32x4 mfma16(bf16x8 a, bf16x8 b, f32x4 c) {
  return __builtin_amdgcn_mfma_f32_16x16x32_bf16(a, b, c, 0, 0, 0);
}

// ---------------- elementwise convert f32 -> bf16 (4/thread) ----------------
__global__ __launch_bounds__(256) void cvt4_k(const float* __restrict__ in,
                                              uint16_t* __restrict__ out, int n4) {
  const int gid = blockIdx.x * 256 + threadIdx.x;
  if (gid >= n4) return;
  const float4 v = ((const float4*)in)[gid];
  ushort4 w; w.x = f2b(v.x); w.y = f2b(v.y); w.z = f2b(v.z); w.w = f2b(v.w);
  ((ushort4*)out)[gid] = w;
}

// ---------------- embedding: x = tok_emb[idx] + pos_emb ----------------
__global__ __launch_bounds__(256) void embed_k(const int* __restrict__ idx,
                                               const float* __restrict__ tok,
                                               const float* __restrict__ pos,
                                               float* __restrict__ x) {
  const int gid = blockIdx.x * 256 + threadIdx.x;      // over MM * (CC/4)
  const int row = gid / (CC / 4), c4 = gid % (CC / 4);
  const int t = row & (TT - 1);
  const int tkn = idx[row];
  const float4 a = ((const float4*)(tok + (size_t)tkn * CC))[c4];
  const float4 q = ((const float4*)(pos + (size_t)t * CC))[c4];
  ((float4*)(x + (size_t)row * CC))[c4] =
      make_float4(a.x + q.x, a.y + q.y, a.z + q.z, a.w + q.w);
}

// ---------------- layernorm: fp32 in -> bf16 out (one wave per row) ----------------
__global__ __launch_bounds__(256) void ln_k(const float* __restrict__ x,
                                            const float* __restrict__ gamma,
                                            const float* __restrict__ beta,
                                            uint16_t* __restrict__ o) {
  const int lane = threadIdx.x & 63, wid = threadIdx.x >> 6;
  const int row = blockIdx.x * 4 + wid;
  const float4* xr = (const float4*)(x + (size_t)row * CC);
  float4 v[3]; float s = 0.f, sq = 0.f;
#pragma unroll
  for (int i = 0; i < 3; ++i) {
    v[i] = xr[lane + i * 64];
    s += v[i].x + v[i].y + v[i].z + v[i].w;
    sq += v[i].x * v[i].x + v[i].y * v[i].y + v[i].z * v[i].z + v[i].w * v[i].w;
  }
#pragma unroll
  for (int m = 1; m < 64; m <<= 1) { s += __shfl_xor(s, m, 64); sq += __shfl_xor(sq, m, 64); }
  const float mu = s * (1.f / 768.f);
  const float rstd = rsqrtf(sq * (1.f / 768.f) - mu * mu + 1e-5f);
  ushort4* orow = (ushort4*)(o + (size_t)row * CC);
#pragma unroll
  for (int i = 0; i < 3; ++i) {
    const int c4 = lane + i * 64;
    const float4 gg = ((const float4*)gamma)[c4];
    const float4 bb = ((const float4*)beta)[c4];
    ushort4 w;
    w.x = f2b((v[i].x - mu) * rstd * gg.x + bb.x);
    w.y = f2b((v[i].y - mu) * rstd * gg.y + bb.y);
    w.z = f2b((v[i].z - mu) * rstd * gg.z + bb.z);
    w.w = f2b((v[i].w - mu) * rstd * gg.w + bb.w);
    orow[c4] = w;
  }
}

// ---------------- transpose + convert: [K][N] f32 -> [N][K] bf16 ----------------
__global__ __launch_bounds__(256) void tconv_k(const float* __restrict__ in,
                                               uint16_t* __restrict__ out, int K, int N) {
  __shared__ float tile[32][33];
  const int kt = blockIdx.x * 32, nt = blockIdx.y * 32;
  const int tx = threadIdx.x & 31, ty = threadIdx.x >> 5;
#pragma unroll
  for (int i = 0; i < 32; i += 8)
    tile[ty + i][tx] = in[(size_t)(kt + ty + i) * N + nt + tx];
  __syncthreads();
#pragma unroll
  for (int i = 0; i < 32; i += 8)
    out[(size_t)(nt + ty + i) * K + kt + tx] = f2b(tile[tx][ty + i]);
}

// ---------------- GEMM: C[M,N] = A[M,K] @ Bt[N,K]^T, bf16 in / f32 accum ----------------
// EPI: 0 = bf16 store; 1 = f32 store; 2 = bias+GELU -> bf16; 3 = resid +=; 4 = resid += (+bias)
template <int EPI>
__global__ __launch_bounds__(256) void gemm_k(const uint16_t* __restrict__ A,
                                              const uint16_t* __restrict__ Bt,
                                              int N, int K,
                                              const float* __restrict__ bias,
                                              float* __restrict__ resid,
                                              uint16_t* __restrict__ outb,
                                              float* __restrict__ outf) {
  __shared__ __align__(16) uint16_t As[128 * 32];
  __shared__ __align__(16) uint16_t Bs[128 * 32];
  const int lane = threadIdx.x & 63, wid = threadIdx.x >> 6;
  const int wm = wid >> 1, wn = wid & 1;
  const int bm = blockIdx.x * 128, bn = blockIdx.y * 128;
  const int rsub = lane >> 2, csub = (lane & 3) * 8;
  f32x4 acc[4][4] = {};
  for (int k0 = 0; k0 < K; k0 += 32) {
#pragma unroll
    for (int q = 0; q < 2; ++q) {
      const int ch = wid * 2 + q;
      gld16(A + (size_t)(bm + ch * 16 + rsub) * K + k0 + csub, &As[ch * 512]);
      gld16(Bt + (size_t)(bn + ch * 16 + rsub) * K + k0 + csub, &Bs[ch * 512]);
    }
    __syncthreads();
    bf16x8 a[4], b[4];
#pragma unroll
    for (int i = 0; i < 4; ++i) {
      a[i] = *(const bf16x8*)&As[(wm * 64 + i * 16 + (lane & 15)) * 32 + (lane >> 4) * 8];
      b[i] = *(const bf16x8*)&Bs[(wn * 64 + i * 16 + (lane & 15)) * 32 + (lane >> 4) * 8];
    }
#pragma unroll
    for (int i = 0; i < 4; ++i)
#pragma unroll
      for (int j = 0; j < 4; ++j)
        acc[i][j] = mfma16(a[i], b[j], acc[i][j]);
    __syncthreads();
  }
#pragma unroll
  for (int i = 0; i < 4; ++i) {
    const int m0 = bm + wm * 64 + i * 16 + ((lane >> 4) << 2);
#pragma unroll
    for (int j = 0; j < 4; ++j) {
      const int n = bn + wn * 64 + j * 16 + (lane & 15);
#pragma unroll
      for (int r = 0; r < 4; ++r) {
        const size_t o = (size_t)(m0 + r) * N + n;
        const float v = acc[i][j][r];
        if constexpr (EPI == 0) {
          outb[o] = f2b(v);
        } else if constexpr (EPI == 1) {
          outf[o] = v;
        } else if constexpr (EPI == 2) {
          float t = v + bias[n];
          t = 0.5f * t * (1.0f + erff(t * 0.70710678118654752f));
          outb[o] = f2b(t);
        } else if constexpr (EPI == 3) {
          resid[o] += v;
        } else {
          resid[o] += v + bias[n];
        }
      }
    }
  }
}

// ---------------- fused causal flash attention ----------------
// grid: (T/64, B*H); block 256 = 4 waves, wave w owns q rows w*16..w*16+15
__global__ __launch_bounds__(256) void attn_k(const uint16_t* __restrict__ qkv,
                                              uint16_t* __restrict__ ao) {
  __shared__ __align__(16) uint16_t Qs[64 * 64], Ks[64 * 64], Vs[64 * 64];
  __shared__ __align__(16) uint16_t Ps[4][16 * 64];
  const int tid = threadIdx.x, lane = tid & 63, wid = tid >> 6;
  const int bh = blockIdx.y, bidx = bh / HH, h = bh % HH;
  const int qt = blockIdx.x;
  const int srow = tid >> 2;            // staging row 0..63 (4 thr/row)
  const int scb = (tid & 3) * 32;       // 32B chunk within 128B row
  const int sel = (tid & 3) * 16;       // element offset within 64
  const int l15 = lane & 15, lhi = lane >> 4;
  // stage Q once (wave-local rows, swizzled)
  {
    const uint16_t* g = qkv + (size_t)(bidx * TT + qt * 64 + srow) * (3 * CC) + h * HDIM + sel;
    uint4 u0 = *(const uint4*)g, u1 = *(const uint4*)(g + 8);
    char* qb = (char*)Qs;
    const int sw = (srow & 7) << 4;
    *(uint4*)(qb + srow * 128 + (scb ^ sw)) = u0;
    *(uint4*)(qb + srow * 128 + ((scb + 16) ^ sw)) = u1;
  }
  f32x4 oacc[4] = {};
  float mrun[4] = {-INFINITY, -INFINITY, -INFINITY, -INFINITY};
  float lrun[4] = {0.f, 0.f, 0.f, 0.f};
  for (int j = 0; j <= qt; ++j) {
    __syncthreads();  // protect Ks/Vs reuse
    {
      const size_t rb = (size_t)(bidx * TT + j * 64 + srow) * (3 * CC);
      const uint16_t* gk = qkv + rb + CC + h * HDIM + sel;
      uint4 u0 = *(const uint4*)gk, u1 = *(const uint4*)(gk + 8);
      char* kb = (char*)Ks;
      const int sw = (srow & 7) << 4;
      *(uint4*)(kb + srow * 128 + (scb ^ sw)) = u0;
      *(uint4*)(kb + srow * 128 + ((scb + 16) ^ sw)) = u1;
      const uint16_t* gv = qkv + rb + 2 * CC + h * HDIM + sel;
      uint16_t vv[16];
      *(uint4*)(vv) = *(const uint4*)gv;
      *(uint4*)(vv + 8) = *(const uint4*)(gv + 8);
      char* vb = (char*)Vs;
#pragma unroll
      for (int d = 0; d < 16; ++d) {
        const int dd = sel + d;
        *(uint16_t*)(vb + dd * 128 + ((srow * 2) ^ ((dd & 7) << 4))) = vv[d];
      }
    }
    __syncthreads();
    // QK^T: S[16 rows][64 cols] per wave
    f32x4 s4[4] = {};
#pragma unroll
    for (int kk = 0; kk < 2; ++kk) {
      const int qrow = wid * 16 + l15;
      const int cbyte = kk * 64 + lhi * 16;
      const bf16x8 qf = *(const bf16x8*)((char*)Qs + qrow * 128 + (cbyte ^ ((qrow & 7) << 4)));
#pragma unroll
      for (int nt = 0; nt < 4; ++nt) {
        const int krow = nt * 16 + l15;
        const bf16x8 kf = *(const bf16x8*)((char*)Ks + krow * 128 + (cbyte ^ ((krow & 7) << 4)));
        s4[nt] = mfma16(qf, kf, s4[nt]);
      }
    }
    // online softmax
    const bool diag = (j == qt);
    float alpha[4];
#pragma unroll
    for (int r = 0; r < 4; ++r) {
      const int qg = qt * 64 + wid * 16 + (lhi << 2) + r;
      float mx = -INFINITY;
#pragma unroll
      for (int nt = 0; nt < 4; ++nt) {
        float v = s4[nt][r] * 0.125f;
        if (diag && (j * 64 + nt * 16 + l15) > qg) v = -INFINITY;
        s4[nt][r] = v;
        mx = fmaxf(mx, v);
      }
#pragma unroll
      for (int m = 1; m < 16; m <<= 1) mx = fmaxf(mx, __shfl_xor(mx, m, 16));
      const float mnew = fmaxf(mrun[r], mx);
      alpha[r] = __expf(mrun[r] - mnew);
      float ps = 0.f;
#pragma unroll
      for (int nt = 0; nt < 4; ++nt) {
        const float pp = __expf(s4[nt][r] - mnew);
        s4[nt][r] = pp;
        ps += pp;
      }
#pragma unroll
      for (int m = 1; m < 16; m <<= 1) ps += __shfl_xor(ps, m, 16);
      lrun[r] = lrun[r] * alpha[r] + ps;
      mrun[r] = mnew;
    }
#pragma unroll
    for (int dt = 0; dt < 4; ++dt)
#pragma unroll
      for (int r = 0; r < 4; ++r) oacc[dt][r] *= alpha[r];
    // P -> per-wave LDS (swizzled)
    char* pb = (char*)Ps[wid];
#pragma unroll
    for (int r = 0; r < 4; ++r) {
      const int prow = (lhi << 2) + r;
      const int swp = (prow & 7) << 4;
#pragma unroll
      for (int nt = 0; nt < 4; ++nt) {
        const int cb = (nt * 16 + l15) * 2;
        *(uint16_t*)(pb + prow * 128 + (cb ^ swp)) = f2b(s4[nt][r]);
      }
    }
    // PV: O += P @ V
#pragma unroll
    for (int kk = 0; kk < 2; ++kk) {
      const int cbyte = kk * 64 + lhi * 16;
      const bf16x8 pf = *(const bf16x8*)(pb + l15 * 128 + (cbyte ^ ((l15 & 7) << 4)));
#pragma unroll
      for (int dt = 0; dt < 4; ++dt) {
        const int vrow = dt * 16 + l15;
        const bf16x8 vf = *(const bf16x8*)((char*)Vs + vrow * 128 + (cbyte ^ ((vrow & 7) << 4)));
        oacc[dt] = mfma16(pf, vf, oacc[dt]);
      }
    }
  }
  // normalize + write
#pragma unroll
  for (int dt = 0; dt < 4; ++dt) {
#pragma unroll
    for (int r = 0; r < 4; ++r) {
      const int q = qt * 64 + wid * 16 + (lhi << 2) + r;
      const float v = oacc[dt][r] / lrun[r];
      ao[(size_t)(bidx * TT + q) * CC + h * HDIM + dt * 16 + l15] = f2b(v);
    }
  }
}

extern "C" void kernel_launch(void* const* d_in, const int* in_sizes, int n_in,
                              void* d_out, int out_size, void* d_ws, size_t ws_size,
                              hipStream_t stream) {
  (void)in_sizes; (void)n_in; (void)out_size; (void)ws_size;
  const int*   idx  = (const int*)d_in[0];
  const float* tok  = (const float*)d_in[1];
  const float* pos  = (const float*)d_in[2];
  const float* Wqkv = (const float*)d_in[3];
  const float* Wpro = (const float*)d_in[4];
  const float* W1   = (const float*)d_in[5];
  const float* b1   = (const float*)d_in[6];
  const float* W2   = (const float*)d_in[7];
  const float* b2   = (const float*)d_in[8];
  const float* g1   = (const float*)d_in[9];
  const float* be1  = (const float*)d_in[10];
  const float* g2   = (const float*)d_in[11];
  const float* be2  = (const float*)d_in[12];
  const float* gf   = (const float*)d_in[13];
  const float* bfb  = (const float*)d_in[14];
  float* out = (float*)d_out;

  char* p = (char*)d_ws;
  float* x = (float*)p;            p += (size_t)MM * CC * 4;        // fp32 residual
  uint16_t* act = (uint16_t*)p;    p += (size_t)MM * CC * 2;        // xn / attn-out (shared)
  uint16_t* big = (uint16_t*)p;    p += (size_t)MM * DFF * 2;       // qkv / h (shared)
  uint16_t* wq = (uint16_t*)p;     p += (size_t)CC * 3 * CC * 2;    // WqkvT bf16
  uint16_t* wp = (uint16_t*)p;     p += (size_t)CC * CC * 2;        // WprojT
  uint16_t* w1 = (uint16_t*)p;     p += (size_t)CC * DFF * 2;       // W1T
  uint16_t* w2 = (uint16_t*)p;     p += (size_t)DFF * CC * 2;       // W2T
  uint16_t* tokb = (uint16_t*)p;   p += (size_t)VV * CC * 2;        // tok_emb bf16

  cvt4_k<<<dim3((VV * CC / 4 + 255) / 256), 256, 0, stream>>>(tok, tokb, VV * CC / 4);
  embed_k<<<dim3(MM * (CC / 4) / 256), 256, 0, stream>>>(idx, tok, pos, x);
  for (int l = 0; l < LNUM; ++l) {
    tconv_k<<<dim3(CC / 32, 3 * CC / 32), 256, 0, stream>>>(Wqkv + (size_t)l * CC * 3 * CC, wq, CC, 3 * CC);
    tconv_k<<<dim3(CC / 32, CC / 32), 256, 0, stream>>>(Wpro + (size_t)l * CC * CC, wp, CC, CC);
    tconv_k<<<dim3(CC / 32, DFF / 32), 256, 0, stream>>>(W1 + (size_t)l * CC * DFF, w1, CC, DFF);
    tconv_k<<<dim3(DFF / 32, CC / 32), 256, 0, stream>>>(W2 + (size_t)l * DFF * CC, w2, DFF, CC);
    ln_k<<<dim3(MM / 4), 256, 0, stream>>>(x, g1 + l * CC, be1 + l * CC, act);
    gemm_k<0><<<dim3(MM / 128, 3 * CC / 128), 256, 0, stream>>>(act, wq, 3 * CC, CC, nullptr, nullptr, big, nullptr);
    attn_k<<<dim3(TT / 64, BB * HH), 256, 0, stream>>>(big, act);
    gemm_k<3><<<dim3(MM / 128, CC / 128), 256, 0, stream>>>(act, wp, CC, CC, nullptr, x, nullptr, nullptr);
    ln_k<<<dim3(MM / 4), 256, 0, stream>>>(x, g2 + l * CC, be2 + l * CC, act);
    gemm_k<2><<<dim3(MM / 128, DFF / 128), 256, 0, stream>>>(act, w1, DFF, CC, b1 + (size_t)l * DFF, nullptr, big, nullptr);
    gemm_k<4><<<dim3(MM / 128, CC / 128), 256, 0, stream>>>(big, w2, CC, DFF, b2 + (size_t)l * CC, x, nullptr, nullptr);
  }
  ln_k<<<dim3(MM / 4), 256, 0, stream>>>(x, gf, bfb, act);
  gemm_k<1><<<dim3(MM / 128, VV / 128), 256, 0, stream>>>(act, tokb, VV, CC, nullptr, nullptr, nullptr, out);
}

// Round 2
// 1948.589 us; speedup vs baseline: 1.1384x; 1.1384x over previous
//
#include <hip/hip_runtime.h>
#include <hip/hip_bf16.h>
#include <stdint.h>

#define LNUM 6
#define BB 8
#define TT 1024
#define CC 768
#define HH 12
#define HDIM 64
#define DFF 3072
#define VV 512
#define MM (BB*TT)
#define QKREG ((size_t)BB*HH*TT*64)   // 6,291,456 elements per q/k/vt region

typedef __bf16 bf16x8 __attribute__((ext_vector_type(8)));
typedef float f32x4 __attribute__((ext_vector_type(4)));

__device__ __forceinline__ uint16_t f2b(float f) {
  uint32_t u = __float_as_uint(f);
  u += 0x7FFFu + ((u >> 16) & 1u);
  return (uint16_t)(u >> 16);
}

__device__ __forceinline__ void gld16(const uint16_t* g, uint16_t* l) {
  __builtin_amdgcn_global_load_lds(
      (const __attribute__((address_space(1))) uint32_t*)g,
      (__attribute__((address_space(3))) uint32_t*)l, 16, 0, 0);
}

__device__ __forceinline__ f32x4 mfma16(bf16x8 a, bf16x8 b, f32x4 c) {
  return __builtin_amdgcn_mfma_f32_16x16x32_bf16(a, b, c, 0, 0, 0);
}

// ---------------- elementwise convert f32 -> bf16 (4/thread) ----------------
__global__ __launch_bounds__(256) void cvt4_k(const float* __restrict__ in,
                                              uint16_t* __restrict__ out, int n4) {
  const int gid = blockIdx.x * 256 + threadIdx.x;
  if (gid >= n4) return;
  const float4 v = ((const float4*)in)[gid];
  ushort4 w; w.x = f2b(v.x); w.y = f2b(v.y); w.z = f2b(v.z); w.w = f2b(v.w);
  ((ushort4*)out)[gid] = w;
}

// ---------------- embedding: x = tok_emb[idx] + pos_emb ----------------
__global__ __launch_bounds__(256) void embed_k(const int* __restrict__ idx,
                                               const float* __restrict__ tok,
                                               const float* __restrict__ pos,
                                               float* __restrict__ x) {
  const int gid = blockIdx.x * 256 + threadIdx.x;      // over MM * (CC/4)
  const int row = gid / (CC / 4), c4 = gid % (CC / 4);
  const int t = row & (TT - 1);
  const int tkn = idx[row];
  const float4 a = ((const float4*)(tok + (size_t)tkn * CC))[c4];
  const float4 q = ((const float4*)(pos + (size_t)t * CC))[c4];
  ((float4*)(x + (size_t)row * CC))[c4] =
      make_float4(a.x + q.x, a.y + q.y, a.z + q.z, a.w + q.w);
}

// ---------------- layernorm: fp32 in -> bf16 out (one wave per row) ----------------
__global__ __launch_bounds__(256) void ln_k(const float* __restrict__ x,
                                            const float* __restrict__ gamma,
                                            const float* __restrict__ beta,
                                            uint16_t* __restrict__ o) {
  const int lane = threadIdx.x & 63, wid = threadIdx.x >> 6;
  const int row = blockIdx.x * 4 + wid;
  const float4* xr = (const float4*)(x + (size_t)row * CC);
  float4 v[3]; float s = 0.f, sq = 0.f;
#pragma unroll
  for (int i = 0; i < 3; ++i) {
    v[i] = xr[lane + i * 64];
    s += v[i].x + v[i].y + v[i].z + v[i].w;
    sq += v[i].x * v[i].x + v[i].y * v[i].y + v[i].z * v[i].z + v[i].w * v[i].w;
  }
#pragma unroll
  for (int m = 1; m < 64; m <<= 1) { s += __shfl_xor(s, m, 64); sq += __shfl_xor(sq, m, 64); }
  const float mu = s * (1.f / 768.f);
  const float rstd = rsqrtf(sq * (1.f / 768.f) - mu * mu + 1e-5f);
  ushort4* orow = (ushort4*)(o + (size_t)row * CC);
#pragma unroll
  for (int i = 0; i < 3; ++i) {
    const int c4 = lane + i * 64;
    const float4 gg = ((const float4*)gamma)[c4];
    const float4 bb = ((const float4*)beta)[c4];
    ushort4 w;
    w.x = f2b((v[i].x - mu) * rstd * gg.x + bb.x);
    w.y = f2b((v[i].y - mu) * rstd * gg.y + bb.y);
    w.z = f2b((v[i].z - mu) * rstd * gg.z + bb.z);
    w.w = f2b((v[i].w - mu) * rstd * gg.w + bb.w);
    orow[c4] = w;
  }
}

// ---------------- transpose + convert: [K][N] f32 -> [N][K] bf16 ----------------
__global__ __launch_bounds__(256) void tconv_k(const float* __restrict__ in,
                                               uint16_t* __restrict__ out, int K, int N) {
  __shared__ float tile[32][33];
  const int kt = blockIdx.x * 32, nt = blockIdx.y * 32;
  const int tx = threadIdx.x & 31, ty = threadIdx.x >> 5;
#pragma unroll
  for (int i = 0; i < 32; i += 8)
    tile[ty + i][tx] = in[(size_t)(kt + ty + i) * N + nt + tx];
  __syncthreads();
#pragma unroll
  for (int i = 0; i < 32; i += 8)
    out[(size_t)(nt + ty + i) * K + kt + tx] = f2b(tile[tx][ty + i]);
}

// ---------------- GEMM: C[M,N] = A[M,K] @ Bt[N,K]^T, bf16 in / f32 accum ----------------
// EPI: 0 = bf16 store; 1 = f32 store; 2 = bias+GELU -> bf16; 3 = resid +=;
//      4 = resid += (+bias); 5 = qkv split (Q,K head-major + V transposed)
template <int EPI>
__global__ __launch_bounds__(256) void gemm_k(const uint16_t* __restrict__ A,
                                              const uint16_t* __restrict__ Bt,
                                              int N, int K,
                                              const float* __restrict__ bias,
                                              float* __restrict__ resid,
                                              uint16_t* __restrict__ outb,
                                              float* __restrict__ outf) {
  __shared__ __align__(16) uint16_t As[128 * 32];
  __shared__ __align__(16) uint16_t Bs[128 * 32];
  const int lane = threadIdx.x & 63, wid = threadIdx.x >> 6;
  const int wm = wid >> 1, wn = wid & 1;
  const int bm = blockIdx.x * 128, bn = blockIdx.y * 128;
  const int rsub = lane >> 2, csub = (lane & 3) * 8;
  f32x4 acc[4][4] = {};
  for (int k0 = 0; k0 < K; k0 += 32) {
#pragma unroll
    for (int q = 0; q < 2; ++q) {
      const int ch = wid * 2 + q;
      gld16(A + (size_t)(bm + ch * 16 + rsub) * K + k0 + csub, &As[ch * 512]);
      gld16(Bt + (size_t)(bn + ch * 16 + rsub) * K + k0 + csub, &Bs[ch * 512]);
    }
    __syncthreads();
    bf16x8 a[4], b[4];
#pragma unroll
    for (int i = 0; i < 4; ++i) {
      a[i] = *(const bf16x8*)&As[(wm * 64 + i * 16 + (lane & 15)) * 32 + (lane >> 4) * 8];
      b[i] = *(const bf16x8*)&Bs[(wn * 64 + i * 16 + (lane & 15)) * 32 + (lane >> 4) * 8];
    }
#pragma unroll
    for (int i = 0; i < 4; ++i)
#pragma unroll
      for (int j = 0; j < 4; ++j)
        acc[i][j] = mfma16(a[i], b[j], acc[i][j]);
    __syncthreads();
  }
#pragma unroll
  for (int i = 0; i < 4; ++i) {
    const int m0 = bm + wm * 64 + i * 16 + ((lane >> 4) << 2);
#pragma unroll
    for (int j = 0; j < 4; ++j) {
      const int n = bn + wn * 64 + j * 16 + (lane & 15);
      if constexpr (EPI == 5) {
        const int sec = n / CC;
        const int rn = n - sec * CC;
        const int hh = rn >> 6, d = rn & 63;
        const int b = m0 >> 10, t0 = m0 & 1023;
        if (sec == 2) {
          ushort4 w;
          w.x = f2b(acc[i][j][0]); w.y = f2b(acc[i][j][1]);
          w.z = f2b(acc[i][j][2]); w.w = f2b(acc[i][j][3]);
          *(ushort4*)(outb + 2 * QKREG + ((size_t)(b * HH + hh) * 64 + d) * TT + t0) = w;
        } else {
          uint16_t* dst = outb + (size_t)sec * QKREG + ((size_t)(b * HH + hh) * TT + t0) * 64 + d;
#pragma unroll
          for (int r = 0; r < 4; ++r) dst[(size_t)r * 64] = f2b(acc[i][j][r]);
        }
      } else {
#pragma unroll
        for (int r = 0; r < 4; ++r) {
          const size_t o = (size_t)(m0 + r) * N + n;
          const float v = acc[i][j][r];
          if constexpr (EPI == 0) {
            outb[o] = f2b(v);
          } else if constexpr (EPI == 1) {
            outf[o] = v;
          } else if constexpr (EPI == 2) {
            float t = v + bias[n];
            t = 0.5f * t * (1.0f + erff(t * 0.70710678118654752f));
            outb[o] = f2b(t);
          } else if constexpr (EPI == 3) {
            resid[o] += v;
          } else if constexpr (EPI == 4) {
            resid[o] += v + bias[n];
          }
        }
      }
    }
  }
}

// ---------------- fused causal flash attention v2 ----------------
// inputs head-major: Q[bh][T][64], K[bh][T][64], Vt[bh][64][T]
// grid: 1536 blocks (qt-major, longest first); block 256 = 4 waves,
// wave w owns q rows qt*64 + w*16 .. +16
__global__ __launch_bounds__(256) void attn_k(const uint16_t* __restrict__ qkvh,
                                              uint16_t* __restrict__ ao) {
  __shared__ __align__(16) uint16_t Ks[64 * 64], Vs[64 * 64];
  __shared__ __align__(16) uint16_t Ps[4][16 * 64];
  const int tid = threadIdx.x, lane = tid & 63, wid = tid >> 6;
  const int qt = (TT / 64 - 1) - blockIdx.x / (BB * HH);   // longest blocks first
  const int bh = blockIdx.x % (BB * HH);
  const uint16_t* qb = qkvh + (size_t)bh * (TT * 64);
  const uint16_t* kb = qkvh + QKREG + (size_t)bh * (TT * 64);
  const uint16_t* vb = qkvh + 2 * QKREG + (size_t)bh * ((size_t)64 * TT);
  const int l15 = lane & 15, lhi = lane >> 4;
  // Q fragments register-resident
  bf16x8 qf[2];
  {
    const uint16_t* qr = qb + (size_t)(qt * 64 + wid * 16 + l15) * 64 + lhi * 8;
    qf[0] = *(const bf16x8*)qr;
    qf[1] = *(const bf16x8*)(qr + 32);
  }
  // staging geometry: chunk c = tid + q*256; row = c>>3 (K: seq row / V: dim row),
  // 16B col (c&7)*16; swizzled LDS dest phys = row*128 + (colb ^ ((row&7)<<4))
  const int c0 = tid, c1 = tid + 256;
  const int r0 = c0 >> 3, r1 = c1 >> 3;
  const int cb0 = (c0 & 7) * 16, cb1 = (c1 & 7) * 16;
  const int ph0 = r0 * 128 + (cb0 ^ ((r0 & 7) << 4));
  const int ph1 = r1 * 128 + (cb1 ^ ((r1 & 7) << 4));

  uint4 kr0, kr1, vr0, vr1;
  // prologue: load tile j=0
  kr0 = *(const uint4*)(kb + (size_t)r0 * 64 + cb0 / 2);
  kr1 = *(const uint4*)(kb + (size_t)r1 * 64 + cb1 / 2);
  vr0 = *(const uint4*)(vb + (size_t)r0 * TT + cb0 / 2);
  vr1 = *(const uint4*)(vb + (size_t)r1 * TT + cb1 / 2);
  *(uint4*)((char*)Ks + ph0) = kr0;
  *(uint4*)((char*)Ks + ph1) = kr1;
  *(uint4*)((char*)Vs + ph0) = vr0;
  *(uint4*)((char*)Vs + ph1) = vr1;
  __syncthreads();

  f32x4 oacc[4] = {};
  float mrun[4] = {-INFINITY, -INFINITY, -INFINITY, -INFINITY};
  float lrun[4] = {0.f, 0.f, 0.f, 0.f};
  char* pb = (char*)Ps[wid];

  for (int j = 0; j <= qt; ++j) {
    const bool more = (j < qt);
    if (more) {  // prefetch next tile into registers (overlaps with compute)
      const int jn = (j + 1) * 64;
      kr0 = *(const uint4*)(kb + (size_t)(jn + r0) * 64 + cb0 / 2);
      kr1 = *(const uint4*)(kb + (size_t)(jn + r1) * 64 + cb1 / 2);
      vr0 = *(const uint4*)(vb + (size_t)r0 * TT + jn + cb0 / 2);
      vr1 = *(const uint4*)(vb + (size_t)r1 * TT + jn + cb1 / 2);
    }
    // ---- QK^T ----
    f32x4 s4[4] = {};
    __builtin_amdgcn_s_setprio(1);
#pragma unroll
    for (int kk = 0; kk < 2; ++kk) {
      const int cbyte = kk * 64 + lhi * 16;
#pragma unroll
      for (int nt = 0; nt < 4; ++nt) {
        const int krow = nt * 16 + l15;
        const bf16x8 kf = *(const bf16x8*)((char*)Ks + krow * 128 + (cbyte ^ ((krow & 7) << 4)));
        s4[nt] = mfma16(qf[kk], kf, s4[nt]);
      }
    }
    __builtin_amdgcn_s_setprio(0);
    // ---- online softmax ----
    const bool diag = (j == qt);
    float alpha[4];
#pragma unroll
    for (int r = 0; r < 4; ++r) {
      const int qg = qt * 64 + wid * 16 + (lhi << 2) + r;
      float mx = -INFINITY;
#pragma unroll
      for (int nt = 0; nt < 4; ++nt) {
        float v = s4[nt][r] * 0.125f;
        if (diag && (j * 64 + nt * 16 + l15) > qg) v = -INFINITY;
        s4[nt][r] = v;
        mx = fmaxf(mx, v);
      }
#pragma unroll
      for (int m = 1; m < 16; m <<= 1) mx = fmaxf(mx, __shfl_xor(mx, m, 16));
      const float mnew = fmaxf(mrun[r], mx);
      alpha[r] = __expf(mrun[r] - mnew);
      float ps = 0.f;
#pragma unroll
      for (int nt = 0; nt < 4; ++nt) {
        const float pp = __expf(s4[nt][r] - mnew);
        s4[nt][r] = pp;
        ps += pp;
      }
#pragma unroll
      for (int m = 1; m < 16; m <<= 1) ps += __shfl_xor(ps, m, 16);
      lrun[r] = lrun[r] * alpha[r] + ps;
      mrun[r] = mnew;
    }
#pragma unroll
    for (int dt = 0; dt < 4; ++dt)
#pragma unroll
      for (int r = 0; r < 4; ++r) oacc[dt][r] *= alpha[r];
    // ---- P -> per-wave LDS (swizzled) ----
#pragma unroll
    for (int r = 0; r < 4; ++r) {
      const int prow = (lhi << 2) + r;
      const int swp = (prow & 7) << 4;
#pragma unroll
      for (int nt = 0; nt < 4; ++nt) {
        const int cb = (nt * 16 + l15) * 2;
        *(uint16_t*)(pb + prow * 128 + (cb ^ swp)) = f2b(s4[nt][r]);
      }
    }
    // ---- PV ----
    __builtin_amdgcn_s_setprio(1);
#pragma unroll
    for (int kk = 0; kk < 2; ++kk) {
      const int cbyte = kk * 64 + lhi * 16;
      const bf16x8 pf = *(const bf16x8*)(pb + l15 * 128 + (cbyte ^ ((l15 & 7) << 4)));
#pragma unroll
      for (int dt = 0; dt < 4; ++dt) {
        const int vrow = dt * 16 + l15;
        const bf16x8 vf = *(const bf16x8*)((char*)Vs + vrow * 128 + (cbyte ^ ((vrow & 7) << 4)));
        oacc[dt] = mfma16(pf, vf, oacc[dt]);
      }
    }
    __builtin_amdgcn_s_setprio(0);
    // ---- commit prefetched tile to LDS ----
    __syncthreads();          // everyone done reading current tile
    if (more) {
      *(uint4*)((char*)Ks + ph0) = kr0;
      *(uint4*)((char*)Ks + ph1) = kr1;
      *(uint4*)((char*)Vs + ph0) = vr0;
      *(uint4*)((char*)Vs + ph1) = vr1;
    }
    __syncthreads();          // writes visible
  }
  // ---- normalize + write ----
#pragma unroll
  for (int dt = 0; dt < 4; ++dt) {
#pragma unroll
    for (int r = 0; r < 4; ++r) {
      const int q = qt * 64 + wid * 16 + (lhi << 2) + r;
      const float v = oacc[dt][r] / lrun[r];
      ao[(size_t)((bh / HH) * TT + q) * CC + (bh % HH) * HDIM + dt * 16 + l15] = f2b(v);
    }
  }
}

extern "C" void kernel_launch(void* const* d_in, const int* in_sizes, int n_in,
                              void* d_out, int out_size, void* d_ws, size_t ws_size,
                              hipStream_t stream) {
  (void)in_sizes; (void)n_in; (void)out_size; (void)ws_size;
  const int*   idx  = (const int*)d_in[0];
  const float* tok  = (const float*)d_in[1];
  const float* pos  = (const float*)d_in[2];
  const float* Wqkv = (const float*)d_in[3];
  const float* Wpro = (const float*)d_in[4];
  const float* W1   = (const float*)d_in[5];
  const float* b1   = (const float*)d_in[6];
  const float* W2   = (const float*)d_in[7];
  const float* b2   = (const float*)d_in[8];
  const float* g1   = (const float*)d_in[9];
  const float* be1  = (const float*)d_in[10];
  const float* g2   = (const float*)d_in[11];
  const float* be2  = (const float*)d_in[12];
  const float* gf   = (const float*)d_in[13];
  const float* bfb  = (const float*)d_in[14];
  float* out = (float*)d_out;

  char* p = (char*)d_ws;
  float* x = (float*)p;            p += (size_t)MM * CC * 4;        // fp32 residual
  uint16_t* act = (uint16_t*)p;    p += (size_t)MM * CC * 2;        // xn / attn-out (shared)
  uint16_t* big = (uint16_t*)p;    p += (size_t)MM * DFF * 2;       // qkv-headmajor / h (shared)
  uint16_t* wq = (uint16_t*)p;     p += (size_t)CC * 3 * CC * 2;    // WqkvT bf16
  uint16_t* wp = (uint16_t*)p;     p += (size_t)CC * CC * 2;        // WprojT
  uint16_t* w1 = (uint16_t*)p;     p += (size_t)CC * DFF * 2;       // W1T
  uint16_t* w2 = (uint16_t*)p;     p += (size_t)DFF * CC * 2;       // W2T
  uint16_t* tokb = (uint16_t*)p;   p += (size_t)VV * CC * 2;        // tok_emb bf16

  cvt4_k<<<dim3((VV * CC / 4 + 255) / 256), 256, 0, stream>>>(tok, tokb, VV * CC / 4);
  embed_k<<<dim3(MM * (CC / 4) / 256), 256, 0, stream>>>(idx, tok, pos, x);
  for (int l = 0; l < LNUM; ++l) {
    tconv_k<<<dim3(CC / 32, 3 * CC / 32), 256, 0, stream>>>(Wqkv + (size_t)l * CC * 3 * CC, wq, CC, 3 * CC);
    tconv_k<<<dim3(CC / 32, CC / 32), 256, 0, stream>>>(Wpro + (size_t)l * CC * CC, wp, CC, CC);
    tconv_k<<<dim3(CC / 32, DFF / 32), 256, 0, stream>>>(W1 + (size_t)l * CC * DFF, w1, CC, DFF);
    tconv_k<<<dim3(DFF / 32, CC / 32), 256, 0, stream>>>(W2 + (size_t)l * DFF * CC, w2, DFF, CC);
    ln_k<<<dim3(MM / 4), 256, 0, stream>>>(x, g1 + l * CC, be1 + l * CC, act);
    gemm_k<5><<<dim3(MM / 128, 3 * CC / 128), 256, 0, stream>>>(act, wq, 3 * CC, CC, nullptr, nullptr, big, nullptr);
    attn_k<<<dim3((TT / 64) * BB * HH), 256, 0, stream>>>(big, act);
    gemm_k<3><<<dim3(MM / 128, CC / 128), 256, 0, stream>>>(act, wp, CC, CC, nullptr, x, nullptr, nullptr);
    ln_k<<<dim3(MM / 4), 256, 0, stream>>>(x, g2 + l * CC, be2 + l * CC, act);
    gemm_k<2><<<dim3(MM / 128, DFF / 128), 256, 0, stream>>>(act, w1, DFF, CC, b1 + (size_t)l * DFF, nullptr, big, nullptr);
    gemm_k<4><<<dim3(MM / 128, CC / 128), 256, 0, stream>>>(big, w2, CC, DFF, b2 + (size_t)l * CC, x, nullptr, nullptr);
  }
  ln_k<<<dim3(MM / 4), 256, 0, stream>>>(x, gf, bfb, act);
  gemm_k<1><<<dim3(MM / 128, VV / 128), 256, 0, stream>>>(act, tokb, VV, CC, nullptr, nullptr, nullptr, out);
}